// Round 1
// baseline (1222.661 us; speedup 1.0000x reference)
//
#include <hip/hip_runtime.h>

#define N_NODES 50000
#define N_EDGES 800000

// ---------------- CSR build ----------------

__global__ void count_kernel(const int* __restrict__ dst, int* __restrict__ cnt, int E) {
    int e = blockIdx.x * blockDim.x + threadIdx.x;
    if (e < E) atomicAdd(&cnt[dst[e]], 1);
}

__global__ void scan_block_kernel(const int* __restrict__ cnt, int* __restrict__ rowptr,
                                  int* __restrict__ bsums, int n) {
    __shared__ int s[256];
    int tid = threadIdx.x;
    int i = blockIdx.x * 256 + tid;
    int v = (i < n) ? cnt[i] : 0;
    s[tid] = v;
    __syncthreads();
    for (int off = 1; off < 256; off <<= 1) {
        int t = (tid >= off) ? s[tid - off] : 0;
        __syncthreads();
        s[tid] += t;
        __syncthreads();
    }
    if (i < n) rowptr[i] = s[tid] - v;   // exclusive
    if (tid == 255) bsums[blockIdx.x] = s[255];
}

__global__ void scan_sums_kernel(int* bsums, int nb) {
    __shared__ int s[256];
    int tid = threadIdx.x;
    int v = (tid < nb) ? bsums[tid] : 0;
    s[tid] = v;
    __syncthreads();
    for (int off = 1; off < 256; off <<= 1) {
        int t = (tid >= off) ? s[tid - off] : 0;
        __syncthreads();
        s[tid] += t;
        __syncthreads();
    }
    if (tid < nb) bsums[tid] = s[tid] - v;  // exclusive, in place
}

__global__ void add_off_kernel(int* __restrict__ rowptr, const int* __restrict__ bsums,
                               int* __restrict__ cursor, int n, int E) {
    int i = blockIdx.x * blockDim.x + threadIdx.x;
    if (i < n) {
        int r = rowptr[i] + bsums[i >> 8];
        rowptr[i] = r;
        cursor[i] = r;
    }
    if (i == 0) rowptr[n] = E;
}

__global__ void fill_kernel(const int* __restrict__ src, const int* __restrict__ dst,
                            int* __restrict__ cursor, int* __restrict__ esrc, int E) {
    int e = blockIdx.x * blockDim.x + threadIdx.x;
    if (e < E) {
        int p = atomicAdd(&cursor[dst[e]], 1);
        esrc[p] = src[e];
    }
}

// ---------------- mean aggregation (CSR gather) ----------------
// 32 lanes per node, float4 per lane (128 channels). 8 nodes per 256-thread block.

__global__ void agg_kernel(const float4* __restrict__ h4, const int* __restrict__ rowptr,
                           const int* __restrict__ esrc, float4* __restrict__ agg4, int n) {
    int g = (blockIdx.x * blockDim.x + threadIdx.x) >> 5;
    int lane = threadIdx.x & 31;
    if (g >= n) return;
    int beg = rowptr[g], end = rowptr[g + 1];
    float ax = 0.f, ay = 0.f, az = 0.f, aw = 0.f;
    for (int k = beg; k < end; ++k) {
        int s = esrc[k];
        float4 v = h4[(size_t)s * 32 + lane];
        ax += v.x; ay += v.y; az += v.z; aw += v.w;
    }
    float inv = (end > beg) ? 1.0f / (float)(end - beg) : 0.0f;
    agg4[(size_t)g * 32 + lane] = make_float4(ax * inv, ay * inv, az * inv, aw * inv);
}

// ---------------- dual GEMM: out = A1@W1 + A2@W2 + b (opt ReLU) ----------------
// K = 128 fixed. BM = 64 rows staged in LDS (phase 0: A1, phase 1: A2).
// Thread tile: TM=8 rows x 4 cols. Weights streamed from global (L1/L2-shared).

template <int DOUT, int NT, bool RELU>
__global__ __launch_bounds__(NT) void gemm_dual(
    const float* __restrict__ A1, const float* __restrict__ A2,
    const float* __restrict__ W1, const float* __restrict__ W2,
    const float* __restrict__ bias, float* __restrict__ out, int M) {
    constexpr int BM = 64, K = 128, LDA = 132;  // LDA pad keeps b128 LDS reads 2-way max
    constexpr int CG = DOUT / 4;                // column groups
    constexpr int RG = NT / CG;                 // row groups
    constexpr int TM = BM / RG;                 // 8
    __shared__ float As[BM * LDA];
    const int tid = threadIdx.x;
    const int cg = tid % CG;
    const int rg = tid / CG;
    const int r0 = blockIdx.x * BM;

    float acc[TM][4];
    const float4 bb = *(const float4*)(bias + cg * 4);
#pragma unroll
    for (int i = 0; i < TM; ++i) {
        acc[i][0] = bb.x; acc[i][1] = bb.y; acc[i][2] = bb.z; acc[i][3] = bb.w;
    }

    const int lrow = tid / (K / 4);
    const int lcol = tid % (K / 4);
    constexpr int RSTEP = NT / (K / 4);
    constexpr int LD = BM / RSTEP;

    for (int ph = 0; ph < 2; ++ph) {
        const float* __restrict__ A = ph ? A2 : A1;
        const float* __restrict__ W = ph ? W2 : W1;
        __syncthreads();
#pragma unroll
        for (int i = 0; i < LD; ++i) {
            int rr = lrow + i * RSTEP;
            int grow = r0 + rr;
            if (grow >= M) grow = M - 1;  // clamp stays inside this block's rows
            float4 v = *(const float4*)(A + (size_t)grow * K + lcol * 4);
            *(float4*)(&As[rr * LDA + lcol * 4]) = v;
        }
        __syncthreads();
#pragma unroll
        for (int k4 = 0; k4 < K / 4; ++k4) {
            const float* Wk = W + (k4 * 4) * DOUT + cg * 4;
            float4 w0 = *(const float4*)(Wk);
            float4 w1 = *(const float4*)(Wk + DOUT);
            float4 w2 = *(const float4*)(Wk + 2 * DOUT);
            float4 w3 = *(const float4*)(Wk + 3 * DOUT);
            float4 a[TM];
#pragma unroll
            for (int i = 0; i < TM; ++i)
                a[i] = *(const float4*)(&As[(rg * TM + i) * LDA + k4 * 4]);
#pragma unroll
            for (int i = 0; i < TM; ++i) {
                acc[i][0] += a[i].x * w0.x + a[i].y * w1.x + a[i].z * w2.x + a[i].w * w3.x;
                acc[i][1] += a[i].x * w0.y + a[i].y * w1.y + a[i].z * w2.y + a[i].w * w3.y;
                acc[i][2] += a[i].x * w0.z + a[i].y * w1.z + a[i].z * w2.z + a[i].w * w3.z;
                acc[i][3] += a[i].x * w0.w + a[i].y * w1.w + a[i].z * w2.w + a[i].w * w3.w;
            }
        }
    }
#pragma unroll
    for (int i = 0; i < TM; ++i) {
        int row = r0 + rg * TM + i;
        if (row < M) {
            float4 o;
            o.x = acc[i][0]; o.y = acc[i][1]; o.z = acc[i][2]; o.w = acc[i][3];
            if (RELU) {
                o.x = fmaxf(o.x, 0.f); o.y = fmaxf(o.y, 0.f);
                o.z = fmaxf(o.z, 0.f); o.w = fmaxf(o.w, 0.f);
            }
            *(float4*)(out + (size_t)row * DOUT + cg * 4) = o;
        }
    }
}

// ---------------- launch ----------------

extern "C" void kernel_launch(void* const* d_in, const int* in_sizes, int n_in,
                              void* d_out, int out_size, void* d_ws, size_t ws_size,
                              hipStream_t stream) {
    const float* x   = (const float*)d_in[0];
    const int* eidx  = (const int*)d_in[1];
    const int* src   = eidx;             // edge_index[0]
    const int* dst   = eidx + N_EDGES;   // edge_index[1]
    const float* Wl0 = (const float*)d_in[2];
    const float* b0  = (const float*)d_in[3];
    const float* Wr0 = (const float*)d_in[4];
    const float* Wl1 = (const float*)d_in[5];
    const float* b1  = (const float*)d_in[6];
    const float* Wr1 = (const float*)d_in[7];
    const float* Wl2 = (const float*)d_in[8];
    const float* b2  = (const float*)d_in[9];
    const float* Wr2 = (const float*)d_in[10];
    float* outp = (float*)d_out;

    // workspace layout (~55 MB)
    float* agg  = (float*)d_ws;                       // N*128 f32
    float* hbuf = agg + (size_t)N_NODES * 128;        // N*128 f32
    int* rowptr = (int*)(hbuf + (size_t)N_NODES * 128);  // N+1
    int* cursor = rowptr + (N_NODES + 1);             // N
    int* esrc   = cursor + N_NODES;                   // E
    int* bsums  = esrc + N_EDGES;                     // ~256

    // --- CSR build (keyed by dst) ---
    hipMemsetAsync(cursor, 0, N_NODES * sizeof(int), stream);
    count_kernel<<<(N_EDGES + 255) / 256, 256, 0, stream>>>(dst, cursor, N_EDGES);
    const int nsb = (N_NODES + 255) / 256;  // 196
    scan_block_kernel<<<nsb, 256, 0, stream>>>(cursor, rowptr, bsums, N_NODES);
    scan_sums_kernel<<<1, 256, 0, stream>>>(bsums, nsb);
    add_off_kernel<<<nsb, 256, 0, stream>>>(rowptr, bsums, cursor, N_NODES, N_EDGES);
    fill_kernel<<<(N_EDGES + 255) / 256, 256, 0, stream>>>(src, dst, cursor, esrc, N_EDGES);

    const int aggGrid = (N_NODES * 32 + 255) / 256;   // 6250
    const int gemmGrid = (N_NODES + 63) / 64;         // 782

    // layer 0: x -> hbuf (ReLU)
    agg_kernel<<<aggGrid, 256, 0, stream>>>((const float4*)x, rowptr, esrc, (float4*)agg, N_NODES);
    gemm_dual<128, 256, true><<<gemmGrid, 256, 0, stream>>>(agg, x, Wl0, Wr0, b0, hbuf, N_NODES);
    // layer 1: hbuf -> hbuf (ReLU, in place: blocks stage own rows before writing)
    agg_kernel<<<aggGrid, 256, 0, stream>>>((const float4*)hbuf, rowptr, esrc, (float4*)agg, N_NODES);
    gemm_dual<128, 256, true><<<gemmGrid, 256, 0, stream>>>(agg, hbuf, Wl1, Wr1, b1, hbuf, N_NODES);
    // layer 2: hbuf -> out (no ReLU, DOUT=64)
    agg_kernel<<<aggGrid, 256, 0, stream>>>((const float4*)hbuf, rowptr, esrc, (float4*)agg, N_NODES);
    gemm_dual<64, 128, false><<<gemmGrid, 128, 0, stream>>>(agg, hbuf, Wl2, Wr2, b2, outp, N_NODES);
}

// Round 2
// 580.792 us; speedup vs baseline: 2.1052x; 2.1052x over previous
//
#include <hip/hip_runtime.h>

#define N_NODES 50000
#define N_EDGES 800000

// ---------------- CSR build ----------------

__global__ void count_kernel(const int* __restrict__ dst, int* __restrict__ cnt, int E) {
    int e = blockIdx.x * blockDim.x + threadIdx.x;
    if (e < E) atomicAdd(&cnt[dst[e]], 1);
}

__global__ void scan_block_kernel(const int* __restrict__ cnt, int* __restrict__ rowptr,
                                  int* __restrict__ bsums, int n) {
    __shared__ int s[256];
    int tid = threadIdx.x;
    int i = blockIdx.x * 256 + tid;
    int v = (i < n) ? cnt[i] : 0;
    s[tid] = v;
    __syncthreads();
    for (int off = 1; off < 256; off <<= 1) {
        int t = (tid >= off) ? s[tid - off] : 0;
        __syncthreads();
        s[tid] += t;
        __syncthreads();
    }
    if (i < n) rowptr[i] = s[tid] - v;   // exclusive
    if (tid == 255) bsums[blockIdx.x] = s[255];
}

__global__ void scan_sums_kernel(int* bsums, int nb) {
    __shared__ int s[256];
    int tid = threadIdx.x;
    int v = (tid < nb) ? bsums[tid] : 0;
    s[tid] = v;
    __syncthreads();
    for (int off = 1; off < 256; off <<= 1) {
        int t = (tid >= off) ? s[tid - off] : 0;
        __syncthreads();
        s[tid] += t;
        __syncthreads();
    }
    if (tid < nb) bsums[tid] = s[tid] - v;  // exclusive, in place
}

__global__ void add_off_kernel(int* __restrict__ rowptr, const int* __restrict__ bsums,
                               int* __restrict__ cursor, int n, int E) {
    int i = blockIdx.x * blockDim.x + threadIdx.x;
    if (i < n) {
        int r = rowptr[i] + bsums[i >> 8];
        rowptr[i] = r;
        cursor[i] = r;
    }
    if (i == 0) rowptr[n] = E;
}

__global__ void fill_kernel(const int* __restrict__ src, const int* __restrict__ dst,
                            int* __restrict__ cursor, int* __restrict__ esrc, int E) {
    int e = blockIdx.x * blockDim.x + threadIdx.x;
    if (e < E) {
        int p = atomicAdd(&cursor[dst[e]], 1);
        esrc[p] = src[e];
    }
}

// ---------------- mean aggregation (CSR gather) ----------------
// 32 lanes per node, float4 per lane (128 channels). 8 nodes per 256-thread block.

__global__ void agg_kernel(const float4* __restrict__ h4, const int* __restrict__ rowptr,
                           const int* __restrict__ esrc, float4* __restrict__ agg4, int n) {
    int g = (blockIdx.x * blockDim.x + threadIdx.x) >> 5;
    int lane = threadIdx.x & 31;
    if (g >= n) return;
    int beg = rowptr[g], end = rowptr[g + 1];
    float ax = 0.f, ay = 0.f, az = 0.f, aw = 0.f;
    for (int k = beg; k < end; ++k) {
        int s = esrc[k];
        float4 v = h4[(size_t)s * 32 + lane];
        ax += v.x; ay += v.y; az += v.z; aw += v.w;
    }
    float inv = (end > beg) ? 1.0f / (float)(end - beg) : 0.0f;
    agg4[(size_t)g * 32 + lane] = make_float4(ax * inv, ay * inv, az * inv, aw * inv);
}

// ---------------- dual GEMM: out = A1@W1 + A2@W2 + b (opt ReLU) ----------------
// K = 128 fixed. BM = 64 rows staged in LDS (phase 0: A1, phase 1: A2).
// Thread tile: TM=8 rows x 4 cols. Weights streamed from global (L1/L2-shared).
// LDS a-reads are wave-broadcast (all lanes of a row-group hit the same addr).
// R1 fix: #pragma unroll 4 (full unroll spilled: VGPR=256, 315MB scratch stores)
//         + __launch_bounds__(NT,4) to cap allocator at 128 VGPRs.

template <int DOUT, int NT, bool RELU>
__global__ __launch_bounds__(NT, 4) void gemm_dual(
    const float* __restrict__ A1, const float* __restrict__ A2,
    const float* __restrict__ W1, const float* __restrict__ W2,
    const float* __restrict__ bias, float* __restrict__ out, int M) {
    constexpr int BM = 64, K = 128, LDA = 132;  // LDA pad keeps b128 LDS reads 2-way max
    constexpr int CG = DOUT / 4;                // column groups
    constexpr int RG = NT / CG;                 // row groups
    constexpr int TM = BM / RG;                 // 8
    __shared__ float As[BM * LDA];
    const int tid = threadIdx.x;
    const int cg = tid % CG;
    const int rg = tid / CG;
    const int r0 = blockIdx.x * BM;

    float acc[TM][4];
    const float4 bb = *(const float4*)(bias + cg * 4);
#pragma unroll
    for (int i = 0; i < TM; ++i) {
        acc[i][0] = bb.x; acc[i][1] = bb.y; acc[i][2] = bb.z; acc[i][3] = bb.w;
    }

    const int lrow = tid / (K / 4);
    const int lcol = tid % (K / 4);
    constexpr int RSTEP = NT / (K / 4);
    constexpr int LD = BM / RSTEP;

    for (int ph = 0; ph < 2; ++ph) {
        const float* __restrict__ A = ph ? A2 : A1;
        const float* __restrict__ W = ph ? W2 : W1;
        __syncthreads();
#pragma unroll
        for (int i = 0; i < LD; ++i) {
            int rr = lrow + i * RSTEP;
            int grow = r0 + rr;
            if (grow >= M) grow = M - 1;  // clamp stays inside this block's rows
            float4 v = *(const float4*)(A + (size_t)grow * K + lcol * 4);
            *(float4*)(&As[rr * LDA + lcol * 4]) = v;
        }
        __syncthreads();
#pragma unroll 4
        for (int k4 = 0; k4 < K / 4; ++k4) {
            const float* Wk = W + (k4 * 4) * DOUT + cg * 4;
            float4 w0 = *(const float4*)(Wk);
            float4 w1 = *(const float4*)(Wk + DOUT);
            float4 w2 = *(const float4*)(Wk + 2 * DOUT);
            float4 w3 = *(const float4*)(Wk + 3 * DOUT);
            float4 a[TM];
#pragma unroll
            for (int i = 0; i < TM; ++i)
                a[i] = *(const float4*)(&As[(rg * TM + i) * LDA + k4 * 4]);
#pragma unroll
            for (int i = 0; i < TM; ++i) {
                acc[i][0] += a[i].x * w0.x + a[i].y * w1.x + a[i].z * w2.x + a[i].w * w3.x;
                acc[i][1] += a[i].x * w0.y + a[i].y * w1.y + a[i].z * w2.y + a[i].w * w3.y;
                acc[i][2] += a[i].x * w0.z + a[i].y * w1.z + a[i].z * w2.z + a[i].w * w3.z;
                acc[i][3] += a[i].x * w0.w + a[i].y * w1.w + a[i].z * w2.w + a[i].w * w3.w;
            }
        }
    }
#pragma unroll
    for (int i = 0; i < TM; ++i) {
        int row = r0 + rg * TM + i;
        if (row < M) {
            float4 o;
            o.x = acc[i][0]; o.y = acc[i][1]; o.z = acc[i][2]; o.w = acc[i][3];
            if (RELU) {
                o.x = fmaxf(o.x, 0.f); o.y = fmaxf(o.y, 0.f);
                o.z = fmaxf(o.z, 0.f); o.w = fmaxf(o.w, 0.f);
            }
            *(float4*)(out + (size_t)row * DOUT + cg * 4) = o;
        }
    }
}

// ---------------- launch ----------------

extern "C" void kernel_launch(void* const* d_in, const int* in_sizes, int n_in,
                              void* d_out, int out_size, void* d_ws, size_t ws_size,
                              hipStream_t stream) {
    const float* x   = (const float*)d_in[0];
    const int* eidx  = (const int*)d_in[1];
    const int* src   = eidx;             // edge_index[0]
    const int* dst   = eidx + N_EDGES;   // edge_index[1]
    const float* Wl0 = (const float*)d_in[2];
    const float* b0  = (const float*)d_in[3];
    const float* Wr0 = (const float*)d_in[4];
    const float* Wl1 = (const float*)d_in[5];
    const float* b1  = (const float*)d_in[6];
    const float* Wr1 = (const float*)d_in[7];
    const float* Wl2 = (const float*)d_in[8];
    const float* b2  = (const float*)d_in[9];
    const float* Wr2 = (const float*)d_in[10];
    float* outp = (float*)d_out;

    // workspace layout (~55 MB)
    float* agg  = (float*)d_ws;                       // N*128 f32
    float* hbuf = agg + (size_t)N_NODES * 128;        // N*128 f32
    int* rowptr = (int*)(hbuf + (size_t)N_NODES * 128);  // N+1
    int* cursor = rowptr + (N_NODES + 1);             // N
    int* esrc   = cursor + N_NODES;                   // E
    int* bsums  = esrc + N_EDGES;                     // ~256

    // --- CSR build (keyed by dst) ---
    hipMemsetAsync(cursor, 0, N_NODES * sizeof(int), stream);
    count_kernel<<<(N_EDGES + 255) / 256, 256, 0, stream>>>(dst, cursor, N_EDGES);
    const int nsb = (N_NODES + 255) / 256;  // 196
    scan_block_kernel<<<nsb, 256, 0, stream>>>(cursor, rowptr, bsums, N_NODES);
    scan_sums_kernel<<<1, 256, 0, stream>>>(bsums, nsb);
    add_off_kernel<<<nsb, 256, 0, stream>>>(rowptr, bsums, cursor, N_NODES, N_EDGES);
    fill_kernel<<<(N_EDGES + 255) / 256, 256, 0, stream>>>(src, dst, cursor, esrc, N_EDGES);

    const int aggGrid = (N_NODES * 32 + 255) / 256;   // 6250
    const int gemmGrid = (N_NODES + 63) / 64;         // 782

    // layer 0: x -> hbuf (ReLU)
    agg_kernel<<<aggGrid, 256, 0, stream>>>((const float4*)x, rowptr, esrc, (float4*)agg, N_NODES);
    gemm_dual<128, 256, true><<<gemmGrid, 256, 0, stream>>>(agg, x, Wl0, Wr0, b0, hbuf, N_NODES);
    // layer 1: hbuf -> hbuf (ReLU, in place: blocks stage own rows before writing)
    agg_kernel<<<aggGrid, 256, 0, stream>>>((const float4*)hbuf, rowptr, esrc, (float4*)agg, N_NODES);
    gemm_dual<128, 256, true><<<gemmGrid, 256, 0, stream>>>(agg, hbuf, Wl1, Wr1, b1, hbuf, N_NODES);
    // layer 2: hbuf -> out (no ReLU, DOUT=64)
    agg_kernel<<<aggGrid, 256, 0, stream>>>((const float4*)hbuf, rowptr, esrc, (float4*)agg, N_NODES);
    gemm_dual<64, 128, false><<<gemmGrid, 128, 0, stream>>>(agg, hbuf, Wl2, Wr2, b2, outp, N_NODES);
}

// Round 3
// 543.871 us; speedup vs baseline: 2.2481x; 1.0679x over previous
//
#include <hip/hip_runtime.h>

#define N_NODES 50000
#define N_EDGES 800000

// ---------------- CSR build ----------------

__global__ void count_kernel(const int* __restrict__ dst, int* __restrict__ cnt, int E) {
    int e = blockIdx.x * blockDim.x + threadIdx.x;
    if (e < E) atomicAdd(&cnt[dst[e]], 1);
}

__global__ void scan_block_kernel(const int* __restrict__ cnt, int* __restrict__ rowptr,
                                  int* __restrict__ bsums, int n) {
    __shared__ int s[256];
    int tid = threadIdx.x;
    int i = blockIdx.x * 256 + tid;
    int v = (i < n) ? cnt[i] : 0;
    s[tid] = v;
    __syncthreads();
    for (int off = 1; off < 256; off <<= 1) {
        int t = (tid >= off) ? s[tid - off] : 0;
        __syncthreads();
        s[tid] += t;
        __syncthreads();
    }
    if (i < n) rowptr[i] = s[tid] - v;   // exclusive
    if (tid == 255) bsums[blockIdx.x] = s[255];
}

__global__ void scan_sums_kernel(int* bsums, int nb) {
    __shared__ int s[256];
    int tid = threadIdx.x;
    int v = (tid < nb) ? bsums[tid] : 0;
    s[tid] = v;
    __syncthreads();
    for (int off = 1; off < 256; off <<= 1) {
        int t = (tid >= off) ? s[tid - off] : 0;
        __syncthreads();
        s[tid] += t;
        __syncthreads();
    }
    if (tid < nb) bsums[tid] = s[tid] - v;  // exclusive, in place
}

__global__ void add_off_kernel(int* __restrict__ rowptr, const int* __restrict__ bsums,
                               int* __restrict__ cursor, int n, int E) {
    int i = blockIdx.x * blockDim.x + threadIdx.x;
    if (i < n) {
        int r = rowptr[i] + bsums[i >> 8];
        rowptr[i] = r;
        cursor[i] = r;
    }
    if (i == 0) rowptr[n] = E;
}

__global__ void fill_kernel(const int* __restrict__ src, const int* __restrict__ dst,
                            int* __restrict__ cursor, int* __restrict__ esrc, int E) {
    int e = blockIdx.x * blockDim.x + threadIdx.x;
    if (e < E) {
        int p = atomicAdd(&cursor[dst[e]], 1);
        esrc[p] = src[e];
    }
}

// ---------------- mean aggregation (CSR gather) ----------------
// 32 lanes per node, float4 per lane (128 channels). 2-way unrolled degree loop
// for 2 independent load/accumulate chains (MLP).

__global__ void agg_kernel(const float4* __restrict__ h4, const int* __restrict__ rowptr,
                           const int* __restrict__ esrc, float4* __restrict__ agg4, int n) {
    int g = (blockIdx.x * blockDim.x + threadIdx.x) >> 5;
    int lane = threadIdx.x & 31;
    if (g >= n) return;
    int beg = rowptr[g], end = rowptr[g + 1];
    float a0x = 0.f, a0y = 0.f, a0z = 0.f, a0w = 0.f;
    float a1x = 0.f, a1y = 0.f, a1z = 0.f, a1w = 0.f;
    int k = beg;
    for (; k + 2 <= end; k += 2) {
        int s0 = esrc[k], s1 = esrc[k + 1];
        float4 v0 = h4[(size_t)s0 * 32 + lane];
        float4 v1 = h4[(size_t)s1 * 32 + lane];
        a0x += v0.x; a0y += v0.y; a0z += v0.z; a0w += v0.w;
        a1x += v1.x; a1y += v1.y; a1z += v1.z; a1w += v1.w;
    }
    if (k < end) {
        int s0 = esrc[k];
        float4 v0 = h4[(size_t)s0 * 32 + lane];
        a0x += v0.x; a0y += v0.y; a0z += v0.z; a0w += v0.w;
    }
    float inv = (end > beg) ? 1.0f / (float)(end - beg) : 0.0f;
    agg4[(size_t)g * 32 + lane] =
        make_float4((a0x + a1x) * inv, (a0y + a1y) * inv, (a0z + a1z) * inv, (a0w + a1w) * inv);
}

// ---------------- dual GEMM: out = A1@W1 + A2@W2 + b (opt ReLU) ----------------
// K = 128 fixed. BM = 32 rows; BOTH A-tiles staged in LDS up front, single fused
// k-loop computes both matmuls (2 independent FMA chains, 8 batched weight loads
// per iter). BM=32 -> 1563 blocks (6.1/CU) for occupancy; NT=256 always.
// R2 lesson: grid 782 x 2 waves gave ~1.5 waves/SIMD -> VALUBusy 17%. This
// version targets ~12 waves/CU (launch_bounds(256,3), LDS 33.8KB).

template <int DOUT, bool RELU>
__global__ __launch_bounds__(256, 3) void gemm_dual(
    const float* __restrict__ A1, const float* __restrict__ A2,
    const float* __restrict__ W1, const float* __restrict__ W2,
    const float* __restrict__ bias, float* __restrict__ out, int M) {
    constexpr int NT = 256, BM = 32, K = 128, LDA = 132;
    constexpr int CG = DOUT / 4;   // 32 (DOUT=128) or 16 (DOUT=64)
    constexpr int RG = NT / CG;    // 8 or 16
    constexpr int TM = BM / RG;    // 4 or 2
    __shared__ float As1[BM * LDA];
    __shared__ float As2[BM * LDA];
    const int tid = threadIdx.x;
    const int cg = tid % CG;
    const int rg = tid / CG;
    const int r0 = blockIdx.x * BM;

    // --- stage both A tiles (coalesced float4) ---
    const int lcol = tid & 31;          // K/4 = 32 column-slots
    const int lrow = tid >> 5;          // 8 row-slots, 4 rows each
#pragma unroll
    for (int i = 0; i < 4; ++i) {
        int rr = lrow + i * 8;
        int grow = r0 + rr;
        if (grow >= M) grow = M - 1;    // clamp stays inside this block's rows
        *(float4*)(&As1[rr * LDA + lcol * 4]) = *(const float4*)(A1 + (size_t)grow * K + lcol * 4);
        *(float4*)(&As2[rr * LDA + lcol * 4]) = *(const float4*)(A2 + (size_t)grow * K + lcol * 4);
    }
    __syncthreads();

    float acc[TM][4];
    const float4 bb = *(const float4*)(bias + cg * 4);
#pragma unroll
    for (int i = 0; i < TM; ++i) {
        acc[i][0] = bb.x; acc[i][1] = bb.y; acc[i][2] = bb.z; acc[i][3] = bb.w;
    }

#pragma unroll 2
    for (int k4 = 0; k4 < K / 4; ++k4) {
        const float* Wk1 = W1 + (k4 * 4) * DOUT + cg * 4;
        const float* Wk2 = W2 + (k4 * 4) * DOUT + cg * 4;
        float4 u0 = *(const float4*)(Wk1);
        float4 u1 = *(const float4*)(Wk1 + DOUT);
        float4 u2 = *(const float4*)(Wk1 + 2 * DOUT);
        float4 u3 = *(const float4*)(Wk1 + 3 * DOUT);
        float4 v0 = *(const float4*)(Wk2);
        float4 v1 = *(const float4*)(Wk2 + DOUT);
        float4 v2 = *(const float4*)(Wk2 + 2 * DOUT);
        float4 v3 = *(const float4*)(Wk2 + 3 * DOUT);
        float4 a1[TM], a2[TM];
#pragma unroll
        for (int i = 0; i < TM; ++i) {
            a1[i] = *(const float4*)(&As1[(rg * TM + i) * LDA + k4 * 4]);
            a2[i] = *(const float4*)(&As2[(rg * TM + i) * LDA + k4 * 4]);
        }
#pragma unroll
        for (int i = 0; i < TM; ++i) {
            acc[i][0] += a1[i].x * u0.x + a1[i].y * u1.x + a1[i].z * u2.x + a1[i].w * u3.x;
            acc[i][1] += a1[i].x * u0.y + a1[i].y * u1.y + a1[i].z * u2.y + a1[i].w * u3.y;
            acc[i][2] += a1[i].x * u0.z + a1[i].y * u1.z + a1[i].z * u2.z + a1[i].w * u3.z;
            acc[i][3] += a1[i].x * u0.w + a1[i].y * u1.w + a1[i].z * u2.w + a1[i].w * u3.w;
            acc[i][0] += a2[i].x * v0.x + a2[i].y * v1.x + a2[i].z * v2.x + a2[i].w * v3.x;
            acc[i][1] += a2[i].x * v0.y + a2[i].y * v1.y + a2[i].z * v2.y + a2[i].w * v3.y;
            acc[i][2] += a2[i].x * v0.z + a2[i].y * v1.z + a2[i].z * v2.z + a2[i].w * v3.z;
            acc[i][3] += a2[i].x * v0.w + a2[i].y * v1.w + a2[i].z * v2.w + a2[i].w * v3.w;
        }
    }

#pragma unroll
    for (int i = 0; i < TM; ++i) {
        int row = r0 + rg * TM + i;
        if (row < M) {
            float4 o;
            o.x = acc[i][0]; o.y = acc[i][1]; o.z = acc[i][2]; o.w = acc[i][3];
            if (RELU) {
                o.x = fmaxf(o.x, 0.f); o.y = fmaxf(o.y, 0.f);
                o.z = fmaxf(o.z, 0.f); o.w = fmaxf(o.w, 0.f);
            }
            *(float4*)(out + (size_t)row * DOUT + cg * 4) = o;
        }
    }
}

// ---------------- launch ----------------

extern "C" void kernel_launch(void* const* d_in, const int* in_sizes, int n_in,
                              void* d_out, int out_size, void* d_ws, size_t ws_size,
                              hipStream_t stream) {
    const float* x   = (const float*)d_in[0];
    const int* eidx  = (const int*)d_in[1];
    const int* src   = eidx;             // edge_index[0]
    const int* dst   = eidx + N_EDGES;   // edge_index[1]
    const float* Wl0 = (const float*)d_in[2];
    const float* b0  = (const float*)d_in[3];
    const float* Wr0 = (const float*)d_in[4];
    const float* Wl1 = (const float*)d_in[5];
    const float* b1  = (const float*)d_in[6];
    const float* Wr1 = (const float*)d_in[7];
    const float* Wl2 = (const float*)d_in[8];
    const float* b2  = (const float*)d_in[9];
    const float* Wr2 = (const float*)d_in[10];
    float* outp = (float*)d_out;

    // workspace layout (~55 MB)
    float* agg  = (float*)d_ws;                       // N*128 f32
    float* hbuf = agg + (size_t)N_NODES * 128;        // N*128 f32
    int* rowptr = (int*)(hbuf + (size_t)N_NODES * 128);  // N+1
    int* cursor = rowptr + (N_NODES + 1);             // N
    int* esrc   = cursor + N_NODES;                   // E
    int* bsums  = esrc + N_EDGES;                     // ~256

    // --- CSR build (keyed by dst) ---
    hipMemsetAsync(cursor, 0, N_NODES * sizeof(int), stream);
    count_kernel<<<(N_EDGES + 255) / 256, 256, 0, stream>>>(dst, cursor, N_EDGES);
    const int nsb = (N_NODES + 255) / 256;  // 196
    scan_block_kernel<<<nsb, 256, 0, stream>>>(cursor, rowptr, bsums, N_NODES);
    scan_sums_kernel<<<1, 256, 0, stream>>>(bsums, nsb);
    add_off_kernel<<<nsb, 256, 0, stream>>>(rowptr, bsums, cursor, N_NODES, N_EDGES);
    fill_kernel<<<(N_EDGES + 255) / 256, 256, 0, stream>>>(src, dst, cursor, esrc, N_EDGES);

    const int aggGrid = (N_NODES * 32 + 255) / 256;   // 6250
    const int gemmGrid = (N_NODES + 31) / 32;         // 1563

    // layer 0: x -> hbuf (ReLU)
    agg_kernel<<<aggGrid, 256, 0, stream>>>((const float4*)x, rowptr, esrc, (float4*)agg, N_NODES);
    gemm_dual<128, true><<<gemmGrid, 256, 0, stream>>>(agg, x, Wl0, Wr0, b0, hbuf, N_NODES);
    // layer 1: hbuf -> hbuf (ReLU, in place: each block stages its own rows first)
    agg_kernel<<<aggGrid, 256, 0, stream>>>((const float4*)hbuf, rowptr, esrc, (float4*)agg, N_NODES);
    gemm_dual<128, true><<<gemmGrid, 256, 0, stream>>>(agg, hbuf, Wl1, Wr1, b1, hbuf, N_NODES);
    // layer 2: hbuf -> out (no ReLU, DOUT=64)
    agg_kernel<<<aggGrid, 256, 0, stream>>>((const float4*)hbuf, rowptr, esrc, (float4*)agg, N_NODES);
    gemm_dual<64, false><<<gemmGrid, 256, 0, stream>>>(agg, hbuf, Wl2, Wr2, b2, outp, N_NODES);
}

// Round 4
// 404.888 us; speedup vs baseline: 3.0197x; 1.3433x over previous
//
#include <hip/hip_runtime.h>

#define N_NODES 50000
#define N_EDGES 800000

typedef __attribute__((ext_vector_type(8))) short short8;
typedef __attribute__((ext_vector_type(4))) float f32x4;

// ---------------- CSR build ----------------

__global__ void count_kernel(const int* __restrict__ dst, int* __restrict__ cnt, int E) {
    int e = blockIdx.x * blockDim.x + threadIdx.x;
    if (e < E) atomicAdd(&cnt[dst[e]], 1);
}

__global__ void scan_block_kernel(const int* __restrict__ cnt, int* __restrict__ rowptr,
                                  int* __restrict__ bsums, int n) {
    __shared__ int s[256];
    int tid = threadIdx.x;
    int i = blockIdx.x * 256 + tid;
    int v = (i < n) ? cnt[i] : 0;
    s[tid] = v;
    __syncthreads();
    for (int off = 1; off < 256; off <<= 1) {
        int t = (tid >= off) ? s[tid - off] : 0;
        __syncthreads();
        s[tid] += t;
        __syncthreads();
    }
    if (i < n) rowptr[i] = s[tid] - v;   // exclusive
    if (tid == 255) bsums[blockIdx.x] = s[255];
}

__global__ void scan_sums_kernel(int* bsums, int nb) {
    __shared__ int s[256];
    int tid = threadIdx.x;
    int v = (tid < nb) ? bsums[tid] : 0;
    s[tid] = v;
    __syncthreads();
    for (int off = 1; off < 256; off <<= 1) {
        int t = (tid >= off) ? s[tid - off] : 0;
        __syncthreads();
        s[tid] += t;
        __syncthreads();
    }
    if (tid < nb) bsums[tid] = s[tid] - v;  // exclusive, in place
}

__global__ void add_off_kernel(int* __restrict__ rowptr, const int* __restrict__ bsums,
                               int* __restrict__ cursor, int n, int E) {
    int i = blockIdx.x * blockDim.x + threadIdx.x;
    if (i < n) {
        int r = rowptr[i] + bsums[i >> 8];
        rowptr[i] = r;
        cursor[i] = r;
    }
    if (i == 0) rowptr[n] = E;
}

__global__ void fill_kernel(const int* __restrict__ src, const int* __restrict__ dst,
                            int* __restrict__ cursor, int* __restrict__ esrc, int E) {
    int e = blockIdx.x * blockDim.x + threadIdx.x;
    if (e < E) {
        int p = atomicAdd(&cursor[dst[e]], 1);
        esrc[p] = src[e];
    }
}

// ---------------- mean aggregation (CSR gather) ----------------

__global__ void agg_kernel(const float4* __restrict__ h4, const int* __restrict__ rowptr,
                           const int* __restrict__ esrc, float4* __restrict__ agg4, int n) {
    int g = (blockIdx.x * blockDim.x + threadIdx.x) >> 5;
    int lane = threadIdx.x & 31;
    if (g >= n) return;
    int beg = rowptr[g], end = rowptr[g + 1];
    float a0x = 0.f, a0y = 0.f, a0z = 0.f, a0w = 0.f;
    float a1x = 0.f, a1y = 0.f, a1z = 0.f, a1w = 0.f;
    int k = beg;
    for (; k + 2 <= end; k += 2) {
        int s0 = esrc[k], s1 = esrc[k + 1];
        float4 v0 = h4[(size_t)s0 * 32 + lane];
        float4 v1 = h4[(size_t)s1 * 32 + lane];
        a0x += v0.x; a0y += v0.y; a0z += v0.z; a0w += v0.w;
        a1x += v1.x; a1y += v1.y; a1z += v1.z; a1w += v1.w;
    }
    if (k < end) {
        int s0 = esrc[k];
        float4 v0 = h4[(size_t)s0 * 32 + lane];
        a0x += v0.x; a0y += v0.y; a0z += v0.z; a0w += v0.w;
    }
    float inv = (end > beg) ? 1.0f / (float)(end - beg) : 0.0f;
    agg4[(size_t)g * 32 + lane] =
        make_float4((a0x + a1x) * inv, (a0y + a1y) * inv, (a0z + a1z) * inv, (a0w + a1w) * inv);
}

// ---------------- split-bf16 helpers ----------------
// f32 = hi(bf16) + lo(bf16) + O(2^-33). GEMM uses Ahi*Bhi + Ahi*Blo + Alo*Bhi.

__device__ inline void split_bf16(float f, unsigned short& hi, unsigned short& lo) {
    union { float f; unsigned u; } a; a.f = f;
    unsigned r = (a.u + 0x7fffu + ((a.u >> 16) & 1u)) >> 16;  // RNE to bf16
    hi = (unsigned short)r;
    union { unsigned u; float f; } b; b.u = r << 16;
    union { float f; unsigned u; } c; c.f = f - b.f;
    unsigned r2 = (c.u + 0x7fffu + ((c.u >> 16) & 1u)) >> 16;
    lo = (unsigned short)r2;
}

// ---------------- weight pre-pack into B-fragment layout ----------------
// Packed layout per matrix: [plane(hi,lo)][ct][ks][lane][j]  (bf16)
//   element = W[k = ks*32 + (lane>>4)*8 + j][n = ct*16 + (lane&15)]
// i.e. the A-rule applied to W^T (m92-verified B^T convention).
// mats 0..3: 128x128 (16384 elems/plane); mats 4..5: 128x64 (8192 elems/plane).

__global__ void pack_w_kernel(const float* __restrict__ W0, const float* __restrict__ W1,
                              const float* __restrict__ W2, const float* __restrict__ W3,
                              const float* __restrict__ W4, const float* __restrict__ W5,
                              unsigned short* __restrict__ out) {
    int t = blockIdx.x * 256 + threadIdx.x;  // 0..81919
    const float* W; int D, local, half; size_t base;
    if (t < 65536) {
        int mat = t >> 14; local = t & 16383; D = 128; half = 16384;
        base = (size_t)mat * 32768;
        W = mat == 0 ? W0 : mat == 1 ? W1 : mat == 2 ? W2 : W3;
    } else {
        int m = (t - 65536) >> 13; local = (t - 65536) & 8191; D = 64; half = 8192;
        base = 131072 + (size_t)m * 16384;
        W = m == 0 ? W4 : W5;
    }
    int j = local & 7, lane = (local >> 3) & 63, ks = (local >> 9) & 3, ct = local >> 11;
    int k = ks * 32 + ((lane >> 4) << 3) + j;
    int n = (ct << 4) + (lane & 15);
    unsigned short hi, lo;
    split_bf16(W[k * D + n], hi, lo);
    out[base + local] = hi;
    out[base + half + local] = lo;
}

// ---------------- dual GEMM via MFMA: out = A1@W1 + A2@W2 + b (opt ReLU) ------
// BM=32 rows/block, 256 thr = 4 waves. A staged in LDS as hi/lo bf16 planes
// (pitch K+8 elems = 272B -> only free 2-way LDS conflicts). Weights read
// pre-packed from global (L1/L2-resident). 96 MFMAs/wave.

template <int DOUT, bool RELU>
__global__ __launch_bounds__(256, 4) void gemm_mfma(
    const float* __restrict__ A1, const float* __restrict__ A2,
    const unsigned short* __restrict__ B1p, const unsigned short* __restrict__ B2p,
    const float* __restrict__ bias, float* __restrict__ out, int M) {
    constexpr int K = 128, BM = 32, KS = 4, CT = DOUT / 16, CPW = CT / 4;
    constexpr int PITCH = K + 8;            // bf16 elems
    constexpr int HALF = CT * KS * 512;     // elems per plane in packed W
    __shared__ unsigned short As[2][2][BM * PITCH];  // [mat][plane][row*PITCH+k]

    const int tid = threadIdx.x;
    const int r0 = blockIdx.x * BM;

    // ---- stage A1, A2 as split bf16 ----
#pragma unroll
    for (int mat = 0; mat < 2; ++mat) {
        const float* __restrict__ A = mat ? A2 : A1;
#pragma unroll
        for (int c = 0; c < 2; ++c) {
            int chunk = tid + c * 256;       // 512 chunks of 8 floats
            int row = chunk >> 4;
            int col8 = (chunk & 15) << 3;
            int grow = r0 + row; if (grow >= M) grow = M - 1;  // clamp inside block rows
            const float* p = A + (size_t)grow * K + col8;
            float4 x0 = *(const float4*)p;
            float4 x1 = *(const float4*)(p + 4);
            float v[8] = {x0.x, x0.y, x0.z, x0.w, x1.x, x1.y, x1.z, x1.w};
            short8 h8, l8;
#pragma unroll
            for (int j = 0; j < 8; ++j) {
                unsigned short h, l;
                split_bf16(v[j], h, l);
                h8[j] = (short)h; l8[j] = (short)l;
            }
            *(short8*)(&As[mat][0][row * PITCH + col8]) = h8;
            *(short8*)(&As[mat][1][row * PITCH + col8]) = l8;
        }
    }
    __syncthreads();

    const int wave = tid >> 6, lane = tid & 63;
    const int rl = lane & 15, quad = lane >> 4;

    f32x4 acc[2][CPW];
#pragma unroll
    for (int c = 0; c < CPW; ++c) {
        float bv = bias[(wave * CPW + c) * 16 + rl];
        acc[0][c] = (f32x4){bv, bv, bv, bv};
        acc[1][c] = acc[0][c];
    }

#pragma unroll
    for (int mat = 0; mat < 2; ++mat) {
        const unsigned short* __restrict__ Bp = mat ? B2p : B1p;
#pragma unroll
        for (int ks = 0; ks < KS; ++ks) {
            short8 a[2][2];
#pragma unroll
            for (int rt = 0; rt < 2; ++rt)
#pragma unroll
                for (int p = 0; p < 2; ++p)
                    a[rt][p] = *(const short8*)(&As[mat][p][(rt * 16 + rl) * PITCH + ks * 32 + quad * 8]);
            short8 b[CPW][2];
#pragma unroll
            for (int c = 0; c < CPW; ++c)
#pragma unroll
                for (int p = 0; p < 2; ++p)
                    b[c][p] = *(const short8*)(Bp + p * HALF +
                                               (((wave * CPW + c) * KS + ks) * 64 + lane) * 8);
#pragma unroll
            for (int rt = 0; rt < 2; ++rt)
#pragma unroll
                for (int c = 0; c < CPW; ++c) {
                    acc[rt][c] = __builtin_amdgcn_mfma_f32_16x16x32_bf16(a[rt][0], b[c][0], acc[rt][c], 0, 0, 0);
                    acc[rt][c] = __builtin_amdgcn_mfma_f32_16x16x32_bf16(a[rt][0], b[c][1], acc[rt][c], 0, 0, 0);
                    acc[rt][c] = __builtin_amdgcn_mfma_f32_16x16x32_bf16(a[rt][1], b[c][0], acc[rt][c], 0, 0, 0);
                }
        }
    }

    // ---- epilogue: C/D layout col=lane&15, row=quad*4+reg (m89-verified) ----
#pragma unroll
    for (int rt = 0; rt < 2; ++rt)
#pragma unroll
        for (int c = 0; c < CPW; ++c) {
            int col = (wave * CPW + c) * 16 + rl;
            int rowb = r0 + rt * 16 + quad * 4;
#pragma unroll
            for (int r = 0; r < 4; ++r) {
                int rr = rowb + r;
                if (rr < M) {
                    float vv = acc[rt][c][r];
                    if (RELU) vv = fmaxf(vv, 0.f);
                    out[(size_t)rr * DOUT + col] = vv;
                }
            }
        }
}

// ---------------- launch ----------------

extern "C" void kernel_launch(void* const* d_in, const int* in_sizes, int n_in,
                              void* d_out, int out_size, void* d_ws, size_t ws_size,
                              hipStream_t stream) {
    const float* x   = (const float*)d_in[0];
    const int* eidx  = (const int*)d_in[1];
    const int* src   = eidx;             // edge_index[0]
    const int* dst   = eidx + N_EDGES;   // edge_index[1]
    const float* Wl0 = (const float*)d_in[2];
    const float* b0  = (const float*)d_in[3];
    const float* Wr0 = (const float*)d_in[4];
    const float* Wl1 = (const float*)d_in[5];
    const float* b1  = (const float*)d_in[6];
    const float* Wr1 = (const float*)d_in[7];
    const float* Wl2 = (const float*)d_in[8];
    const float* b2  = (const float*)d_in[9];
    const float* Wr2 = (const float*)d_in[10];
    float* outp = (float*)d_out;

    // workspace layout (~56 MB), all sub-regions 16B-aligned
    float* agg  = (float*)d_ws;                          // N*128 f32
    float* hbuf = agg + (size_t)N_NODES * 128;           // N*128 f32
    int* rowptr = (int*)(hbuf + (size_t)N_NODES * 128);  // 50016 ints (padded)
    int* cursor = rowptr + 50016;                        // N
    int* esrc   = cursor + N_NODES;                      // E
    int* bsums  = esrc + N_EDGES;                        // 256
    unsigned short* packw = (unsigned short*)(bsums + 256);  // 163840 bf16 = 320KB
    unsigned short* Wl0p = packw;                // 32768 each (hi+lo) for 128x128
    unsigned short* Wr0p = packw + 32768;
    unsigned short* Wl1p = packw + 65536;
    unsigned short* Wr1p = packw + 98304;
    unsigned short* Wl2p = packw + 131072;       // 16384 each for 128x64
    unsigned short* Wr2p = packw + 147456;

    // --- weight pre-pack (independent of CSR chain) ---
    pack_w_kernel<<<320, 256, 0, stream>>>(Wl0, Wr0, Wl1, Wr1, Wl2, Wr2, packw);

    // --- CSR build (keyed by dst) ---
    hipMemsetAsync(cursor, 0, N_NODES * sizeof(int), stream);
    count_kernel<<<(N_EDGES + 255) / 256, 256, 0, stream>>>(dst, cursor, N_EDGES);
    const int nsb = (N_NODES + 255) / 256;  // 196
    scan_block_kernel<<<nsb, 256, 0, stream>>>(cursor, rowptr, bsums, N_NODES);
    scan_sums_kernel<<<1, 256, 0, stream>>>(bsums, nsb);
    add_off_kernel<<<nsb, 256, 0, stream>>>(rowptr, bsums, cursor, N_NODES, N_EDGES);
    fill_kernel<<<(N_EDGES + 255) / 256, 256, 0, stream>>>(src, dst, cursor, esrc, N_EDGES);

    const int aggGrid = (N_NODES * 32 + 255) / 256;   // 6250
    const int gemmGrid = (N_NODES + 31) / 32;         // 1563

    // layer 0: x -> hbuf (ReLU)
    agg_kernel<<<aggGrid, 256, 0, stream>>>((const float4*)x, rowptr, esrc, (float4*)agg, N_NODES);
    gemm_mfma<128, true><<<gemmGrid, 256, 0, stream>>>(agg, x, Wl0p, Wr0p, b0, hbuf, N_NODES);
    // layer 1: hbuf -> hbuf (ReLU, in place: each block stages its own rows first)
    agg_kernel<<<aggGrid, 256, 0, stream>>>((const float4*)hbuf, rowptr, esrc, (float4*)agg, N_NODES);
    gemm_mfma<128, true><<<gemmGrid, 256, 0, stream>>>(agg, hbuf, Wl1p, Wr1p, b1, hbuf, N_NODES);
    // layer 2: hbuf -> out (no ReLU, DOUT=64)
    agg_kernel<<<aggGrid, 256, 0, stream>>>((const float4*)hbuf, rowptr, esrc, (float4*)agg, N_NODES);
    gemm_mfma<64, false><<<gemmGrid, 256, 0, stream>>>(agg, hbuf, Wl2p, Wr2p, b2, outp, N_NODES);
}

// Round 5
// 404.826 us; speedup vs baseline: 3.0202x; 1.0002x over previous
//
#include <hip/hip_runtime.h>

#define N_NODES 50000
#define N_EDGES 800000

typedef __attribute__((ext_vector_type(8))) short short8;
typedef __attribute__((ext_vector_type(4))) float f32x4;
typedef __attribute__((ext_vector_type(4))) unsigned short ushort4v;
typedef __attribute__((ext_vector_type(8))) unsigned short ushort8v;

// ---------------- CSR build ----------------

__global__ void count_kernel(const int* __restrict__ dst, int* __restrict__ cnt, int E) {
    int e = blockIdx.x * blockDim.x + threadIdx.x;
    if (e < E) atomicAdd(&cnt[dst[e]], 1);
}

__global__ void scan_block_kernel(const int* __restrict__ cnt, int* __restrict__ rowptr,
                                  int* __restrict__ bsums, int n) {
    __shared__ int s[256];
    int tid = threadIdx.x;
    int i = blockIdx.x * 256 + tid;
    int v = (i < n) ? cnt[i] : 0;
    s[tid] = v;
    __syncthreads();
    for (int off = 1; off < 256; off <<= 1) {
        int t = (tid >= off) ? s[tid - off] : 0;
        __syncthreads();
        s[tid] += t;
        __syncthreads();
    }
    if (i < n) rowptr[i] = s[tid] - v;   // exclusive
    if (tid == 255) bsums[blockIdx.x] = s[255];
}

__global__ void scan_sums_kernel(int* bsums, int nb) {
    __shared__ int s[256];
    int tid = threadIdx.x;
    int v = (tid < nb) ? bsums[tid] : 0;
    s[tid] = v;
    __syncthreads();
    for (int off = 1; off < 256; off <<= 1) {
        int t = (tid >= off) ? s[tid - off] : 0;
        __syncthreads();
        s[tid] += t;
        __syncthreads();
    }
    if (tid < nb) bsums[tid] = s[tid] - v;  // exclusive, in place
}

__global__ void add_off_kernel(int* __restrict__ rowptr, const int* __restrict__ bsums,
                               int* __restrict__ cursor, int n, int E) {
    int i = blockIdx.x * blockDim.x + threadIdx.x;
    if (i < n) {
        int r = rowptr[i] + bsums[i >> 8];
        rowptr[i] = r;
        cursor[i] = r;
    }
    if (i == 0) rowptr[n] = E;
}

__global__ void fill_kernel(const int* __restrict__ src, const int* __restrict__ dst,
                            int* __restrict__ cursor, int* __restrict__ esrc, int E) {
    int e = blockIdx.x * blockDim.x + threadIdx.x;
    if (e < E) {
        int p = atomicAdd(&cursor[dst[e]], 1);
        esrc[p] = src[e];
    }
}

// ---------------- split-bf16 helpers ----------------
// f32 = hi(bf16) + lo(bf16) + O(2^-33). GEMM uses Ahi*Bhi + Ahi*Blo + Alo*Bhi.

__device__ inline void split_bf16(float f, unsigned short& hi, unsigned short& lo) {
    union { float f; unsigned u; } a; a.f = f;
    unsigned r = (a.u + 0x7fffu + ((a.u >> 16) & 1u)) >> 16;  // RNE to bf16
    hi = (unsigned short)r;
    union { unsigned u; float f; } b; b.u = r << 16;
    union { float f; unsigned u; } c; c.f = f - b.f;
    unsigned r2 = (c.u + 0x7fffu + ((c.u >> 16) & 1u)) >> 16;
    lo = (unsigned short)r2;
}

__device__ inline float bf2f(unsigned short u) {
    union { unsigned u; float f; } a; a.u = (unsigned)u << 16; return a.f;
}

// ---------------- split x into hi/lo bf16 planes ----------------

__global__ void split_x_kernel(const float* __restrict__ x, unsigned short* __restrict__ hi,
                               unsigned short* __restrict__ lo, int n4) {
    int t = blockIdx.x * 256 + threadIdx.x;   // one float4 per thread
    if (t >= n4) return;
    float4 v = *(const float4*)(x + (size_t)t * 4);
    float vv[4] = {v.x, v.y, v.z, v.w};
    ushort4v h, l;
#pragma unroll
    for (int j = 0; j < 4; ++j) {
        unsigned short a, b;
        split_bf16(vv[j], a, b);
        h[j] = a; l[j] = b;
    }
    *(ushort4v*)(hi + (size_t)t * 4) = h;
    *(ushort4v*)(lo + (size_t)t * 4) = l;
}

// ---------------- weight pre-pack into B-fragment layout ----------------
// Packed layout per matrix: [plane(hi,lo)][ct][ks][lane][j]  (bf16)
//   element = W[k = ks*32 + (lane>>4)*8 + j][n = ct*16 + (lane&15)]
// mats 0..3: 128x128 (16384 elems/plane); mats 4..5: 128x64 (8192 elems/plane).

__global__ void pack_w_kernel(const float* __restrict__ W0, const float* __restrict__ W1,
                              const float* __restrict__ W2, const float* __restrict__ W3,
                              const float* __restrict__ W4, const float* __restrict__ W5,
                              unsigned short* __restrict__ out) {
    int t = blockIdx.x * 256 + threadIdx.x;  // 0..81919
    const float* W; int D, local, half; size_t base;
    if (t < 65536) {
        int mat = t >> 14; local = t & 16383; D = 128; half = 16384;
        base = (size_t)mat * 32768;
        W = mat == 0 ? W0 : mat == 1 ? W1 : mat == 2 ? W2 : W3;
    } else {
        int m = (t - 65536) >> 13; local = (t - 65536) & 8191; D = 64; half = 8192;
        base = 131072 + (size_t)m * 16384;
        W = m == 0 ? W4 : W5;
    }
    int j = local & 7, lane = (local >> 3) & 63, ks = (local >> 9) & 3, ct = local >> 11;
    int k = ks * 32 + ((lane >> 4) << 3) + j;
    int n = (ct << 4) + (lane & 15);
    unsigned short hi, lo;
    split_bf16(W[k * D + n], hi, lo);
    out[base + local] = hi;
    out[base + half + local] = lo;
}

// ---------------- fused SAGE layer ----------------
// out = mean_{neighbors}(Hhi) @ W1 + (Hhi+Hlo) @ W2 + b   [opt ReLU]
// BM=32 dst rows/block, 256 thr = 4 waves. Gather reads only the hi plane
// (halves gather traffic; rel err 2^-9 per neighbor). Self path reads hi+lo
// (f32-accurate). Both staged into LDS bf16 planes, then 16x16x32 MFMA with
// pre-packed weights. SPLIT_OUT: write hi/lo planes for next layer; else f32.

template <int DOUT, bool RELU, bool SPLIT_OUT>
__global__ __launch_bounds__(256, 4) void sage_fused(
    const unsigned short* __restrict__ Hhi, const unsigned short* __restrict__ Hlo,
    const int* __restrict__ rowptr, const int* __restrict__ esrc,
    const unsigned short* __restrict__ B1p, const unsigned short* __restrict__ B2p,
    const float* __restrict__ bias, float* __restrict__ outf,
    unsigned short* __restrict__ outhi, unsigned short* __restrict__ outlo, int M) {
    constexpr int K = 128, BM = 32, KS = 4, CT = DOUT / 16, CPW = CT / 4;
    constexpr int PITCH = K + 8;
    constexpr int HALF = CT * KS * 512;
    __shared__ unsigned short As[2][2][BM * PITCH];  // [agg/self][hi/lo][row*PITCH+k]

    const int tid = threadIdx.x;
    const int r0 = blockIdx.x * BM;

    // ---- self rows -> As[1] (planes copied verbatim) ----
#pragma unroll
    for (int c = 0; c < 2; ++c) {
        int chunk = tid + c * 256;          // 512 chunks = 32 rows x 16 x (8 bf16)
        int row = chunk >> 4;
        int c8 = (chunk & 15) * 8;
        int grow = r0 + row; if (grow >= M) grow = M - 1;
        ushort8v h = *(const ushort8v*)(Hhi + (size_t)grow * K + c8);
        ushort8v l = *(const ushort8v*)(Hlo + (size_t)grow * K + c8);
        *(ushort8v*)(&As[1][0][row * PITCH + c8]) = h;
        *(ushort8v*)(&As[1][1][row * PITCH + c8]) = l;
    }

    // ---- gather-mean (hi plane only) -> As[0] ----
    const int grp = tid >> 5, l32 = tid & 31;   // 8 groups x 32 lanes; 4 rows/group
#pragma unroll
    for (int i = 0; i < 4; ++i) {
        int row = grp * 4 + i;
        int grow = r0 + row; if (grow >= M) grow = M - 1;
        int beg = rowptr[grow], end = rowptr[grow + 1];
        float s0 = 0.f, s1 = 0.f, s2 = 0.f, s3 = 0.f;
        float t0 = 0.f, t1 = 0.f, t2 = 0.f, t3 = 0.f;
        int k = beg;
        for (; k + 2 <= end; k += 2) {
            int e0 = esrc[k], e1 = esrc[k + 1];
            ushort4v v0 = *(const ushort4v*)(Hhi + (size_t)e0 * K + l32 * 4);
            ushort4v v1 = *(const ushort4v*)(Hhi + (size_t)e1 * K + l32 * 4);
            s0 += bf2f(v0[0]); s1 += bf2f(v0[1]); s2 += bf2f(v0[2]); s3 += bf2f(v0[3]);
            t0 += bf2f(v1[0]); t1 += bf2f(v1[1]); t2 += bf2f(v1[2]); t3 += bf2f(v1[3]);
        }
        if (k < end) {
            int e0 = esrc[k];
            ushort4v v0 = *(const ushort4v*)(Hhi + (size_t)e0 * K + l32 * 4);
            s0 += bf2f(v0[0]); s1 += bf2f(v0[1]); s2 += bf2f(v0[2]); s3 += bf2f(v0[3]);
        }
        float inv = (end > beg) ? 1.0f / (float)(end - beg) : 0.0f;
        float m[4] = {(s0 + t0) * inv, (s1 + t1) * inv, (s2 + t2) * inv, (s3 + t3) * inv};
        ushort4v mh, ml;
#pragma unroll
        for (int j = 0; j < 4; ++j) {
            unsigned short a, b;
            split_bf16(m[j], a, b);
            mh[j] = a; ml[j] = b;
        }
        *(ushort4v*)(&As[0][0][row * PITCH + l32 * 4]) = mh;
        *(ushort4v*)(&As[0][1][row * PITCH + l32 * 4]) = ml;
    }
    __syncthreads();

    // ---- MFMA ----
    const int wave = tid >> 6, lane = tid & 63;
    const int rl = lane & 15, quad = lane >> 4;

    f32x4 acc[2][CPW];
#pragma unroll
    for (int c = 0; c < CPW; ++c) {
        float bv = bias[(wave * CPW + c) * 16 + rl];
        acc[0][c] = (f32x4){bv, bv, bv, bv};
        acc[1][c] = acc[0][c];
    }

#pragma unroll
    for (int mat = 0; mat < 2; ++mat) {
        const unsigned short* __restrict__ Bp = mat ? B2p : B1p;
#pragma unroll
        for (int ks = 0; ks < KS; ++ks) {
            short8 a[2][2];
#pragma unroll
            for (int rt = 0; rt < 2; ++rt)
#pragma unroll
                for (int p = 0; p < 2; ++p)
                    a[rt][p] = *(const short8*)(&As[mat][p][(rt * 16 + rl) * PITCH + ks * 32 + quad * 8]);
            short8 b[CPW][2];
#pragma unroll
            for (int c = 0; c < CPW; ++c)
#pragma unroll
                for (int p = 0; p < 2; ++p)
                    b[c][p] = *(const short8*)(Bp + p * HALF +
                                               (((wave * CPW + c) * KS + ks) * 64 + lane) * 8);
#pragma unroll
            for (int rt = 0; rt < 2; ++rt)
#pragma unroll
                for (int c = 0; c < CPW; ++c) {
                    acc[rt][c] = __builtin_amdgcn_mfma_f32_16x16x32_bf16(a[rt][0], b[c][0], acc[rt][c], 0, 0, 0);
                    acc[rt][c] = __builtin_amdgcn_mfma_f32_16x16x32_bf16(a[rt][0], b[c][1], acc[rt][c], 0, 0, 0);
                    acc[rt][c] = __builtin_amdgcn_mfma_f32_16x16x32_bf16(a[rt][1], b[c][0], acc[rt][c], 0, 0, 0);
                }
        }
    }

    // ---- epilogue: C/D layout col=lane&15, row=quad*4+reg ----
#pragma unroll
    for (int rt = 0; rt < 2; ++rt)
#pragma unroll
        for (int c = 0; c < CPW; ++c) {
            int col = (wave * CPW + c) * 16 + rl;
            int rowb = r0 + rt * 16 + quad * 4;
#pragma unroll
            for (int r = 0; r < 4; ++r) {
                int rr = rowb + r;
                if (rr < M) {
                    float vv = acc[rt][c][r];
                    if (RELU) vv = fmaxf(vv, 0.f);
                    if (SPLIT_OUT) {
                        unsigned short h, l;
                        split_bf16(vv, h, l);
                        outhi[(size_t)rr * DOUT + col] = h;
                        outlo[(size_t)rr * DOUT + col] = l;
                    } else {
                        outf[(size_t)rr * DOUT + col] = vv;
                    }
                }
            }
        }
}

// ---------------- launch ----------------

extern "C" void kernel_launch(void* const* d_in, const int* in_sizes, int n_in,
                              void* d_out, int out_size, void* d_ws, size_t ws_size,
                              hipStream_t stream) {
    const float* x   = (const float*)d_in[0];
    const int* eidx  = (const int*)d_in[1];
    const int* src   = eidx;             // edge_index[0]
    const int* dst   = eidx + N_EDGES;   // edge_index[1]
    const float* Wl0 = (const float*)d_in[2];
    const float* b0  = (const float*)d_in[3];
    const float* Wr0 = (const float*)d_in[4];
    const float* Wl1 = (const float*)d_in[5];
    const float* b1  = (const float*)d_in[6];
    const float* Wr1 = (const float*)d_in[7];
    const float* Wl2 = (const float*)d_in[8];
    const float* b2  = (const float*)d_in[9];
    const float* Wr2 = (const float*)d_in[10];
    float* outp = (float*)d_out;

    // workspace (~55 MB): activation planes ping-pong x* <-> h1*
    unsigned short* xhi  = (unsigned short*)d_ws;           // N*128 each
    unsigned short* xlo  = xhi + (size_t)N_NODES * 128;
    unsigned short* h1hi = xlo + (size_t)N_NODES * 128;
    unsigned short* h1lo = h1hi + (size_t)N_NODES * 128;
    int* rowptr = (int*)(h1lo + (size_t)N_NODES * 128);     // 50016 (padded)
    int* cursor = rowptr + 50016;                           // N
    int* esrc   = cursor + N_NODES;                         // E
    int* bsums  = esrc + N_EDGES;                           // 256
    unsigned short* packw = (unsigned short*)(bsums + 256); // 163840 bf16
    unsigned short* Wl0p = packw;
    unsigned short* Wr0p = packw + 32768;
    unsigned short* Wl1p = packw + 65536;
    unsigned short* Wr1p = packw + 98304;
    unsigned short* Wl2p = packw + 131072;
    unsigned short* Wr2p = packw + 147456;

    // --- weight pack + x split (independent of CSR chain) ---
    pack_w_kernel<<<320, 256, 0, stream>>>(Wl0, Wr0, Wl1, Wr1, Wl2, Wr2, packw);
    split_x_kernel<<<6250, 256, 0, stream>>>(x, xhi, xlo, N_NODES * 32);

    // --- CSR build (keyed by dst) ---
    hipMemsetAsync(cursor, 0, N_NODES * sizeof(int), stream);
    count_kernel<<<(N_EDGES + 255) / 256, 256, 0, stream>>>(dst, cursor, N_EDGES);
    const int nsb = (N_NODES + 255) / 256;  // 196
    scan_block_kernel<<<nsb, 256, 0, stream>>>(cursor, rowptr, bsums, N_NODES);
    scan_sums_kernel<<<1, 256, 0, stream>>>(bsums, nsb);
    add_off_kernel<<<nsb, 256, 0, stream>>>(rowptr, bsums, cursor, N_NODES, N_EDGES);
    fill_kernel<<<(N_EDGES + 255) / 256, 256, 0, stream>>>(src, dst, cursor, esrc, N_EDGES);

    const int grid = (N_NODES + 31) / 32;   // 1563

    // layer 0: x -> h1 (ReLU, split planes)
    sage_fused<128, true, true><<<grid, 256, 0, stream>>>(
        xhi, xlo, rowptr, esrc, Wl0p, Wr0p, b0, nullptr, h1hi, h1lo, N_NODES);
    // layer 1: h1 -> x-slots (ReLU, split planes; ping-pong, no in-place hazard)
    sage_fused<128, true, true><<<grid, 256, 0, stream>>>(
        h1hi, h1lo, rowptr, esrc, Wl1p, Wr1p, b1, nullptr, xhi, xlo, N_NODES);
    // layer 2: x-slots -> out (no ReLU, f32, DOUT=64)
    sage_fused<64, false, false><<<grid, 256, 0, stream>>>(
        xhi, xlo, rowptr, esrc, Wl2p, Wr2p, b2, outp, nullptr, nullptr, N_NODES);
}